// Round 6
// baseline (135.259 us; speedup 1.0000x reference)
//
#include <hip/hip_runtime.h>
#include <hip/hip_bf16.h>
#include <math.h>

typedef __bf16 bf16x8 __attribute__((ext_vector_type(8)));
typedef float f32x4 __attribute__((ext_vector_type(4)));
typedef unsigned int u32;
typedef u32 u32x4 __attribute__((ext_vector_type(4)));
typedef u32 u32x2 __attribute__((ext_vector_type(2)));

// Problem constants: B=8, C=256, H=W=64, O=256, K=9, GN groups=32 (8 ch each)
// xT layout (granule-major): [b][cg=32][pix=4096][8ch] bf16; granule = 16B.
//   byte offset = (b<<21) + (cg<<16) + pix*16

__device__ inline u32 pack2bf16(float a, float b) {
  u32 ua = __float_as_uint(a);
  u32 ub = __float_as_uint(b);
  ua += 0x7fffu + ((ua >> 16) & 1u);   // RNE
  ub += 0x7fffu + ((ub >> 16) & 1u);
  return (ua >> 16) | (ub & 0xffff0000u);
}

// ---------------------------------------------------------------------------
// K0: prep — pack w_dcn into swizzled bf16 tiles, pack w_off into swizzled
// bf16 tiles (O padded 18->32), zero stats.
// ---------------------------------------------------------------------------
__global__ void prep(const float* __restrict__ w_dcn, const float* __restrict__ w_off,
                     unsigned short* __restrict__ wT4, unsigned short* __restrict__ wOffT,
                     float* __restrict__ stats) {
  size_t id = (size_t)blockIdx.x * 256 + threadIdx.x;
  if (id < 589824) {               // 256 o * 2304 ck
    int o  = (int)(id / 2304);
    int ck = (int)(id % 2304);     // ck = k*256 + c
    int k = ck >> 8, c = ck & 255;
    float v = w_dcn[(size_t)(o * 256 + c) * 9 + k];
    u32 uv = __float_as_uint(v);
    uv += 0x7fffu + ((uv >> 16) & 1u);
    int tile = ck >> 6, kk = ck & 63;
    int lin = o * 128 + kk * 2;
    int swz = lin ^ ((o & 7) << 4);
    *(unsigned short*)((char*)wT4 + (size_t)tile * 32768 + swz) = (unsigned short)(uv >> 16);
  } else if (id < 663552) {        // 36 tiles * 32 o * 64 kk = 73728
    int r = (int)(id - 589824);
    int tile = r >> 11;            // k*4 + cc
    int rr = r & 2047;
    int o = rr >> 6, kk = rr & 63;
    int k = tile >> 2, cc = tile & 3;
    int c = (cc << 6) + kk;
    float v = (o < 18) ? w_off[(size_t)(o * 256 + c) * 9 + k] : 0.f;
    u32 uv = __float_as_uint(v);
    uv += 0x7fffu + ((uv >> 16) & 1u);
    int swz = (o * 128 + kk * 2) ^ ((o & 7) << 4);
    *(unsigned short*)((char*)wOffT + (size_t)tile * 4096 + swz) = (unsigned short)(uv >> 16);
  } else if (id < 664064) {        // zero stats: 512 floats
    stats[id - 663552] = 0.f;
  }
}

// ---------------------------------------------------------------------------
// K1: transpose x [B][C][H][W] -> xT granule-major [b][cg][pix][8ch] bf16
// grid: 8 b * 64 y * 4 cchunk = 2048 blocks of 256
// ---------------------------------------------------------------------------
__global__ __launch_bounds__(256) void transpose_x(const float* __restrict__ x,
                                                   unsigned short* __restrict__ xT) {
  __shared__ float tl[64][65];
  int bx = blockIdx.x;
  int b = bx >> 8;
  int y = (bx >> 2) & 63;
  int cb = (bx & 3) << 6;          // 64-ch chunk base
  int t = threadIdx.x;
  int xi = t & 63, cr = t >> 6;
  size_t base = (((size_t)(b * 256 + cb) * 64 + y) << 6);
#pragma unroll
  for (int rep = 0; rep < 16; ++rep) {
    int cl = rep * 4 + cr;
    tl[cl][xi] = x[base + (size_t)cl * 4096 + xi];
  }
  __syncthreads();
  int xw = t & 63, cpair = t >> 6;   // cpair in [0,4)
#pragma unroll
  for (int r = 0; r < 2; ++r) {
    int cgl = cpair * 2 + r;         // local granule in this 64-ch chunk
    int cg = (cb >> 3) + cgl;
    u32 pk4[4];
#pragma unroll
    for (int i = 0; i < 4; ++i)
      pk4[i] = pack2bf16(tl[cgl * 8 + 2 * i][xw], tl[cgl * 8 + 2 * i + 1][xw]);
    u32x4 v = {pk4[0], pk4[1], pk4[2], pk4[3]};
    *(u32x4*)((char*)xT + (((size_t)b << 21)) + ((size_t)cg << 16) + ((y << 6) + xw) * 16) = v;
  }
}

// ---------------------------------------------------------------------------
// K2: offset conv via MFMA, pipelined: issue loads(t+1) -> MFMA(t) ->
// write(t+1). A: [2][64][64] bf16 XOR-swizzled; B via global_load_lds.
// Sampling from granule-major xT (coalesced).
// ---------------------------------------------------------------------------
__global__ __launch_bounds__(256, 2) void conv_offset_mfma(
    const unsigned short* __restrict__ xT, const unsigned short* __restrict__ wOffT,
    float* __restrict__ offs) {
  __shared__ unsigned short A[2][64][64];  // 16KB, byte ^= (row&7)<<4
  __shared__ unsigned short Bo[2][2048];   // 8KB  ([32 o][64 kk], swizzled)
  const int bx = blockIdx.x;
  const int lb = ((bx & 7) << 6) + (bx >> 3);   // XCD x -> image x
  const int b = lb >> 6;
  const int y = lb & 63;
  const int t = threadIdx.x;
  const int lane = t & 63, wid = t >> 6;
  const char* xTbB = (const char*)xT + ((size_t)b << 21);
  const int p = t >> 2;            // pixel in row (= xx)

  f32x4 acc[2];
  {
    f32x4 z = {0.f, 0.f, 0.f, 0.f};
    acc[0] = z; acc[1] = z;
  }

  u32x4 ra = {0u,0u,0u,0u}, rb = {0u,0u,0u,0u};

  auto issue = [&](int tt, int d) {
    int k = tt >> 2, cc = tt & 3;
    int ky = k / 3, kx = k - ky * 3;
    int ys = y - 1 + ky;
    int xs = p - 1 + kx;
    bool ok = ((unsigned)ys < 64u) && ((unsigned)xs < 64u);
    u32x4 z = {0u,0u,0u,0u};
    ra = z; rb = z;
    if (ok) {
      int cg0 = (cc << 3) + ((t & 3) << 1);
      const char* s0 = xTbB + ((size_t)cg0 << 16) + (((ys << 6) + xs) << 4);
      ra = *(const u32x4*)s0;
      rb = *(const u32x4*)(s0 + 65536);
    }
    __builtin_amdgcn_global_load_lds(
        (const __attribute__((address_space(1))) u32*)((const char*)wOffT + ((size_t)tt << 12) + (wid << 10) + (lane << 4)),
        (__attribute__((address_space(3))) u32*)((char*)&Bo[d][0] + (wid << 10)),
        16, 0, 0);
  };
  auto writeA = [&](int d) {
    char* dst = (char*)&A[d][0][0] + p * 128;
    int b0 = (t & 3) << 5;
    int sw = (p & 7) << 4;
    *(u32x4*)(dst + (b0 ^ sw)) = ra;
    *(u32x4*)(dst + ((b0 + 16) ^ sw)) = rb;
  };

  issue(0, 0);
  writeA(0);
  __syncthreads();

  int cur = 0;
  for (int tt = 0; tt < 36; ++tt) {
    if (tt < 35) issue(tt + 1, cur ^ 1);
#pragma unroll
    for (int s = 0; s < 2; ++s) {
      int row = (wid << 4) + (lane & 15);
      int bir = ((s << 6) + ((lane >> 4) << 4)) ^ ((row & 7) << 4);
      bf16x8 a = *(const bf16x8*)((const char*)&A[cur][0][0] + row * 128 + bir);
#pragma unroll
      for (int j = 0; j < 2; ++j) {
        int o = (j << 4) + (lane & 15);
        int kb = ((s << 6) + ((lane >> 4) << 4)) ^ ((o & 7) << 4);
        bf16x8 bv = *(const bf16x8*)((const char*)&Bo[cur][0] + o * 128 + kb);
        acc[j] = __builtin_amdgcn_mfma_f32_16x16x32_bf16(a, bv, acc[j], 0, 0, 0);
      }
    }
    if (tt < 35) writeA(cur ^ 1);
    __syncthreads();
    cur ^= 1;
  }

#pragma unroll
  for (int j = 0; j < 2; ++j) {
    int o = (j << 4) + (lane & 15);
    if (o < 18) {
#pragma unroll
      for (int r = 0; r < 4; ++r) {
        int pl = (wid << 4) + ((lane >> 4) << 2) + r;
        offs[((size_t)b * 4096 + (y << 6) + pl) * 18 + o] = acc[j][r];
      }
    }
  }
}

// ---------------------------------------------------------------------------
// K4: main fused kernel — producer/consumer waves + granule-major sampling.
// block = 128 px x 256 O, 512 thr: waves 0-3 consumers (wave wc owns
// 128px x 64o, acc[8][4]); waves 4-7 producers. Producer wave = 64
// consecutive px x 32-ch half -> sample loads are lane-coalesced
// (adjacent px -> adjacent 16B granules).
// ---------------------------------------------------------------------------
union Arena {
  struct {
    unsigned short A[2][128][64];   // 32,768 B (byte ^= (row&7)<<4)
    unsigned short Bt[2][16384];    // 65,536 B ([256 o][64 kk] swz)
  } m;
  unsigned short ytile[256][136];   // 69,632 B (o-major epilogue buffer)
};

__global__ __launch_bounds__(512, 2) void dcn_main(
    const unsigned short* __restrict__ xT, const float* __restrict__ offs,
    const float* __restrict__ boff, const unsigned short* __restrict__ wT4,
    unsigned short* __restrict__ yb, float* __restrict__ stats) {
  __shared__ Arena ar;
  __shared__ unsigned short poffu[9][128][4];  //  9,216 B  [k][px][corner]
  __shared__ float pw[9][128][4];              // 18,432 B  [k][px][corner]

  const int bx = blockIdx.x;
  const int lb = ((bx & 7) << 5) + (bx >> 3);   // XCD x -> image x
  const int b = lb >> 5;
  const int pxbase = (lb & 31) << 7;            // 128-px group (2 rows)
  const int t = threadIdx.x;
  const int lane = t & 63, wid = t >> 6;
  const bool is_cons = (wid < 4);
  const int obase = (wid & 3) << 6;             // consumer o-block
  const char* xTbB = (const char*)xT + ((size_t)b << 21);

  // producer mapping: pwid in [0,4): px = (pwid&1)*64 + lane (consecutive!),
  // chhalf = pwid>>1 (which 32-ch half of the 64-ck step chunk)
  const int pwid = wid - 4;
  const int p_my = ((pwid & 1) << 6) + lane;
  const int chalf = pwid >> 1;

  // --- per-(pixel,k) sampling params into LDS (all waves) ---
  for (int idx = t; idx < 1152; idx += 512) {
    int p = idx / 9, k = idx - p * 9;
    int pxg = pxbase + p;
    int yy = pxg >> 6, xx = pxg & 63;
    const float* op = offs + ((size_t)b * 4096 + pxg) * 18 + k * 2;
    int kyi = k / 3, kxi = k - kyi * 3;
    float py = op[0] + boff[k * 2] + (float)(yy - 1 + kyi);
    float pxf = op[1] + boff[k * 2 + 1] + (float)(xx - 1 + kxi);
    float fy = floorf(py), fx = floorf(pxf);
    float dy = py - fy, dx = pxf - fx;
    int y0 = (int)fy, x0 = (int)fx;
    int y1 = y0 + 1, x1 = x0 + 1;
    float vy0 = ((unsigned)y0 < 64u) ? 1.f : 0.f;
    float vy1 = ((unsigned)y1 < 64u) ? 1.f : 0.f;
    float vx0 = ((unsigned)x0 < 64u) ? 1.f : 0.f;
    float vx1 = ((unsigned)x1 < 64u) ? 1.f : 0.f;
    int y0c = min(max(y0, 0), 63), y1c = min(max(y1, 0), 63);
    int x0c = min(max(x0, 0), 63), x1c = min(max(x1, 0), 63);
    poffu[k][p][0] = (unsigned short)((y0c << 6) + x0c);
    poffu[k][p][1] = (unsigned short)((y0c << 6) + x1c);
    poffu[k][p][2] = (unsigned short)((y1c << 6) + x0c);
    poffu[k][p][3] = (unsigned short)((y1c << 6) + x1c);
    pw[k][p][0] = (1.f - dy) * (1.f - dx) * vy0 * vx0;
    pw[k][p][1] = (1.f - dy) * dx * vy0 * vx1;
    pw[k][p][2] = dy * (1.f - dx) * vy1 * vx0;
    pw[k][p][3] = dy * dx * vy1 * vx1;
  }

  f32x4 acc[8][4];
#pragma unroll
  for (int i = 0; i < 8; ++i)
#pragma unroll
    for (int j = 0; j < 4; ++j) {
      f32x4 z = {0.f, 0.f, 0.f, 0.f};
      acc[i][j] = z;
    }

  __syncthreads();                 // params ready

  // producer: sample+pack A(nt) and stage B(nt) into buffer d
  auto stage = [&](int nt, int d) {
    int k = nt >> 2, cc = nt & 3;
    int cgb = (cc << 3) + (chalf << 2);          // granule plane base
    const char* s0 = xTbB + ((int)poffu[k][p_my][0] << 4);
    const char* s1 = xTbB + ((int)poffu[k][p_my][1] << 4);
    const char* s2 = xTbB + ((int)poffu[k][p_my][2] << 4);
    const char* s3 = xTbB + ((int)poffu[k][p_my][3] << 4);
    u32x4 r0[4], r1[4], r2[4], r3[4];
#pragma unroll
    for (int v = 0; v < 4; ++v) {
      size_t po = ((size_t)(cgb + v) << 16);
      r0[v] = *(const u32x4*)(s0 + po);
      r1[v] = *(const u32x4*)(s1 + po);
      r2[v] = *(const u32x4*)(s2 + po);
      r3[v] = *(const u32x4*)(s3 + po);
    }
    // B: async global->LDS, 8KB per producer wave (linear, pre-swizzled src)
    {
      const char* src = (const char*)wT4 + ((size_t)nt << 15) + (pwid << 13);
      char* dstb = (char*)&ar.m.Bt[d][0] + (pwid << 13);
#pragma unroll
      for (int i2 = 0; i2 < 8; ++i2) {
        __builtin_amdgcn_global_load_lds(
            (const __attribute__((address_space(1))) u32*)(src + (i2 << 10) + (lane << 4)),
            (__attribute__((address_space(3))) u32*)(dstb + (i2 << 10)),
            16, 0, 0);
      }
    }
    float w0 = pw[k][p_my][0], w1 = pw[k][p_my][1];
    float w2 = pw[k][p_my][2], w3 = pw[k][p_my][3];
    char* dst = (char*)&ar.m.A[d][0][0] + p_my * 128;
    int sw = (p_my & 7) << 4;
#pragma unroll
    for (int v = 0; v < 4; ++v) {
      u32 o4[4];
#pragma unroll
      for (int e = 0; e < 4; ++e) {
        u32 u0 = r0[v][e], u1 = r1[v][e], u2 = r2[v][e], u3 = r3[v][e];
        float lo = w0 * __uint_as_float(u0 << 16);
        lo = fmaf(w1, __uint_as_float(u1 << 16), lo);
        lo = fmaf(w2, __uint_as_float(u2 << 16), lo);
        lo = fmaf(w3, __uint_as_float(u3 << 16), lo);
        float hi = w0 * __uint_as_float(u0 & 0xffff0000u);
        hi = fmaf(w1, __uint_as_float(u1 & 0xffff0000u), hi);
        hi = fmaf(w2, __uint_as_float(u2 & 0xffff0000u), hi);
        hi = fmaf(w3, __uint_as_float(u3 & 0xffff0000u), hi);
        u32 r;
        asm("v_cvt_pk_bf16_f32 %0, %1, %2" : "=v"(r) : "v"(lo), "v"(hi));
        o4[e] = r;
      }
      u32x4 ov = {o4[0], o4[1], o4[2], o4[3]};
      *(u32x4*)(dst + (((chalf << 6) + (v << 4)) ^ sw)) = ov;
    }
  };

  if (!is_cons) stage(0, 0);
  __syncthreads();

  int cur = 0;
  for (int tt = 0; tt < 36; ++tt) {
    if (is_cons) {
      const char* Abase = (const char*)&ar.m.A[cur][0][0];
      const char* Bbase = (const char*)&ar.m.Bt[cur][0];
      __builtin_amdgcn_s_setprio(1);
#pragma unroll
      for (int s = 0; s < 2; ++s) {
        int kx = (s << 6) + ((lane >> 4) << 4);
        int swl = (lane & 7) << 4;
        bf16x8 a[8], bb[4];
#pragma unroll
        for (int i = 0; i < 8; ++i)
          a[i] = *(const bf16x8*)(Abase + ((i << 4) + (lane & 15)) * 128 + (kx ^ swl));
#pragma unroll
        for (int j = 0; j < 4; ++j)
          bb[j] = *(const bf16x8*)(Bbase + (obase + (j << 4) + (lane & 15)) * 128 + (kx ^ swl));
#pragma unroll
        for (int i = 0; i < 8; ++i)
#pragma unroll
          for (int j = 0; j < 4; ++j)
            acc[i][j] = __builtin_amdgcn_mfma_f32_16x16x32_bf16(a[i], bb[j], acc[i][j], 0, 0, 0);
      }
      __builtin_amdgcn_s_setprio(0);
    } else {
      if (tt < 35) stage(tt + 1, cur ^ 1);
    }
    __syncthreads();
    cur ^= 1;
  }

  if (is_cons) {
    // --- GroupNorm partial sums ---
#pragma unroll
    for (int j = 0; j < 4; ++j) {
      float s1 = 0.f, s2 = 0.f;
#pragma unroll
      for (int i = 0; i < 8; ++i)
#pragma unroll
        for (int r = 0; r < 4; ++r) {
          float v = acc[i][j][r];
          s1 += v;
          s2 += v * v;
        }
      s1 += __shfl_xor(s1, 1, 64);  s2 += __shfl_xor(s2, 1, 64);
      s1 += __shfl_xor(s1, 2, 64);  s2 += __shfl_xor(s2, 2, 64);
      s1 += __shfl_xor(s1, 4, 64);  s2 += __shfl_xor(s2, 4, 64);
      s1 += __shfl_xor(s1, 16, 64); s2 += __shfl_xor(s2, 16, 64);
      s1 += __shfl_xor(s1, 32, 64); s2 += __shfl_xor(s2, 32, 64);
      if ((lane & 0x37) == 0) {     // lanes 0 and 8: one per 8-channel group
        int g = (obase + (j << 4) + (lane & 15)) >> 3;
        atomicAdd(&stats[((b << 5) + g) * 2 + 0], s1);
        atomicAdd(&stats[((b << 5) + g) * 2 + 1], s2);
      }
    }
    // --- acc -> ytile[o][px] bf16 ---
#pragma unroll
    for (int i = 0; i < 8; ++i)
#pragma unroll
      for (int j = 0; j < 4; ++j) {
        int o = obase + (j << 4) + (lane & 15);
        int pxr = (i << 4) + ((lane >> 4) << 2);
        u32 w0, w1;
        asm("v_cvt_pk_bf16_f32 %0, %1, %2" : "=v"(w0) : "v"(acc[i][j][0]), "v"(acc[i][j][1]));
        asm("v_cvt_pk_bf16_f32 %0, %1, %2" : "=v"(w1) : "v"(acc[i][j][2]), "v"(acc[i][j][3]));
        u32x2 wv = {w0, w1};
        *(u32x2*)((char*)ar.ytile + o * 272 + pxr * 2) = wv;
      }
  }
  __syncthreads();
  {
    int o = t >> 1, hf = t & 1;
    const char* srcb = (const char*)ar.ytile + o * 272 + (hf << 7);
    unsigned short* dst = yb + (((size_t)(b * 256 + o)) << 12) + pxbase + (hf << 6);
#pragma unroll
    for (int qq = 0; qq < 8; ++qq)
      *(u32x4*)((char*)dst + (qq << 4)) = *(const u32x4*)(srcb + (qq << 4));
  }
}

// ---------------------------------------------------------------------------
// K5: GroupNorm finalize + Mish — pure streaming.
// ---------------------------------------------------------------------------
__global__ __launch_bounds__(256) void gn_mish(const unsigned short* __restrict__ yb,
                                               const float* __restrict__ stats,
                                               const float* __restrict__ gamma,
                                               const float* __restrict__ beta,
                                               float* __restrict__ out) {
  int v = blockIdx.x * 512 + threadIdx.x;
#pragma unroll
  for (int it = 0; it < 2; ++it, v += 256) {
    int o = (v >> 9) & 255;
    int b = v >> 17;
    float s1 = stats[((b << 5) + (o >> 3)) * 2 + 0];
    float s2 = stats[((b << 5) + (o >> 3)) * 2 + 1];
    float mean = s1 * (1.f / 32768.f);
    float var = s2 * (1.f / 32768.f) - mean * mean;
    float rstd = rsqrtf(var + 1e-5f);
    float ga = gamma[o] * rstd, be = beta[o] - mean * gamma[o] * rstd;
    u32x4 u = *(const u32x4*)(yb + ((size_t)v << 3));
    float res[8];
#pragma unroll
    for (int e = 0; e < 4; ++e) {
      float va = __uint_as_float(u[e] << 16);
      float vb = __uint_as_float(u[e] & 0xffff0000u);
      float v0 = fmaf(va, ga, be);
      float v1 = fmaf(vb, ga, be);
      float e0 = expf(fminf(v0, 15.f));
      float e1 = expf(fminf(v1, 15.f));
      float n0 = e0 * (e0 + 2.f);
      float n1 = e1 * (e1 + 2.f);
      float m0 = v0 * (n0 / (n0 + 2.f));
      float m1 = v1 * (n1 / (n1 + 2.f));
      if (v0 > 15.f) m0 = v0;
      if (v1 > 15.f) m1 = v1;
      res[2 * e] = m0;
      res[2 * e + 1] = m1;
    }
    f32x4 o0 = {res[0], res[1], res[2], res[3]};
    f32x4 o1 = {res[4], res[5], res[6], res[7]};
    float* dst = out + ((size_t)v << 3);
    *(f32x4*)dst = o0;
    *((f32x4*)dst + 1) = o1;
  }
}

// ---------------------------------------------------------------------------
extern "C" void kernel_launch(void* const* d_in, const int* in_sizes, int n_in,
                              void* d_out, int out_size, void* d_ws, size_t ws_size,
                              hipStream_t stream) {
  const float* x     = (const float*)d_in[0];
  const float* w_off = (const float*)d_in[1];
  const float* b_off = (const float*)d_in[2];
  const float* w_dcn = (const float*)d_in[3];
  const float* gamma = (const float*)d_in[4];
  const float* beta  = (const float*)d_in[5];
  float* out = (float*)d_out;
  char* ws = (char*)d_ws;
  unsigned short* xT   = (unsigned short*)(ws);              // 16,777,216 B (bf16)
  unsigned short* yb   = (unsigned short*)(ws + 16777216);   // 16,777,216 B (bf16)
  float* offs          = (float*)(ws + 33554432);            //  2,359,296 B
  unsigned short* wT4  = (unsigned short*)(ws + 35913728);   //  1,179,648 B
  unsigned short* wOffT= (unsigned short*)(ws + 37093376);   //    147,456 B
  float* stats         = (float*)(ws + 37240832);            //      2,048 B
  prep<<<dim3(2594), dim3(256), 0, stream>>>(w_dcn, w_off, wT4, wOffT, stats);
  transpose_x<<<dim3(2048), dim3(256), 0, stream>>>(x, xT);
  conv_offset_mfma<<<dim3(512), dim3(256), 0, stream>>>(xT, wOffT, offs);
  dcn_main<<<dim3(256), dim3(512), 0, stream>>>(xT, offs, b_off, wT4, yb, stats);
  gn_mish<<<dim3(2048), dim3(256), 0, stream>>>(yb, stats, gamma, beta, out);
}